// Round 6
// baseline (1117.044 us; speedup 1.0000x reference)
//
#include <hip/hip_runtime.h>
#include <hip/hip_bf16.h>
#include <cstdint>

typedef __hip_bfloat16 bf16;
using short8 = __attribute__((ext_vector_type(8))) short;
using short4v = __attribute__((ext_vector_type(4))) short;
using f32x4  = __attribute__((ext_vector_type(4))) float;
using f4     = __attribute__((ext_vector_type(4))) float;

#define DEV __device__ __forceinline__

static constexpr int Bb = 8;
static constexpr int S  = 2048;
static constexpr int D  = 1024;
static constexpr long ROWS = (long)Bb * S;   // 16384
static constexpr int N1 = 1280;              // 512(cc1) + 256(be1) + 512(cr1-x)
static constexpr int NCH = 64;               // scan chunks (32 rows each) -- round-1 config
static constexpr int MT2 = 64;               // 256-row tiles = ROWS/256

DEV void async_copy16(const void* g, void* l) {
    __builtin_amdgcn_global_load_lds((const __attribute__((address_space(1))) void*)g,
                                     (__attribute__((address_space(3))) void*)l,
                                     16, 0, 0);
}

DEV float wsum(float v) {
#pragma unroll
    for (int off = 32; off > 0; off >>= 1) v += __shfl_xor(v, off, 64);
    return v;
}

DEV float bf2f(bf16 x) { return __bfloat162float(x); }
DEV bf16  f2bf(float x) { return __float2bfloat16(x); }
DEV short f2bfbits(float v) { bf16 h = f2bf(v); short s; __builtin_memcpy(&s, &h, 2); return s; }
DEV float bits2f(short s) {
    unsigned u = ((unsigned)(unsigned short)s) << 16;
    float f; __builtin_memcpy(&f, &u, 4); return f;
}

// -------- single prep kernel: 4 tiled transposes (fp32->bf16 B^T) + W2T + bias concat ------
// tiles: [0,128) cc1 | [128,192) be1 | [192,320) cr1 | [320,832) cd1 | 832 small stuff
__global__ __launch_bounds__(256) void prep_all(
    const float* __restrict__ Wcc1, const float* __restrict__ Wbe1,
    const float* __restrict__ Wcr1, const float* __restrict__ Wcd1,
    const float* __restrict__ Wcc2,
    const float* __restrict__ b1, const float* __restrict__ b2, const float* __restrict__ b3,
    bf16* __restrict__ WT1, bf16* __restrict__ WT2,
    float* __restrict__ W2T, float* __restrict__ biasA)
{
    const int bid = blockIdx.x, t = threadIdx.x;
    if (bid == 832) {
        for (int i = t; i < 2560; i += 256) {
            int cc = i >> 9, n = i & 511;
            W2T[i] = Wcc2[(long)n * 5 + cc];
        }
        for (int i = t; i < N1; i += 256) {
            float v;
            if (i < 512)       v = b1[i];
            else if (i < 768)  v = b2[i - 512];
            else               v = b3[i - 768];
            biasA[i] = v;
        }
        return;
    }
    const float* W; int ldw; bf16* dst; long dstLd, dstOff; int nt, kt;
    if (bid < 128)      { W = Wcc1; ldw = 512;  dst = WT1; dstLd = 1024; dstOff = 0;
                          nt = bid & 7; kt = bid >> 3; }
    else if (bid < 192) { W = Wbe1; ldw = 256;  dst = WT1; dstLd = 1024; dstOff = (long)512 * 1024;
                          int lb = bid - 128; nt = lb & 3; kt = lb >> 2; }
    else if (bid < 320) { W = Wcr1; ldw = 512;  dst = WT1; dstLd = 1024; dstOff = (long)768 * 1024;
                          int lb = bid - 192; nt = lb & 7; kt = lb >> 3; }
    else                { W = Wcd1; ldw = 1024; dst = WT2; dstLd = 2048; dstOff = 0;
                          int lb = bid - 320; nt = lb & 15; kt = lb >> 4; }

    __shared__ float tile[64][65];
    const int tx = t & 63, ty = t >> 6;
    const int k64 = kt * 64, n64 = nt * 64;
#pragma unroll
    for (int p = 0; p < 16; ++p) {
        int k = ty * 16 + p;
        tile[k][tx] = W[(long)(k64 + k) * ldw + n64 + tx];
    }
    __syncthreads();
#pragma unroll
    for (int p = 0; p < 16; ++p) {
        int n = ty * 16 + p;
        dst[dstOff + (long)(n64 + n) * dstLd + k64 + tx] = f2bf(tile[tx][n]);
    }
}

// -------- scan phase A: per-chunk partial sums, float4 lanes (chunk = 32 rows) --------
__global__ __launch_bounds__(256) void scan_partial4(const float* __restrict__ x,
                                                     float* __restrict__ part) {
    const int t = threadIdx.x, c = blockIdx.x, b = blockIdx.y;
    const float* p = x + ((long)b * S + (long)c * 32) * D + t * 4;
    f4 s = {0.f, 0.f, 0.f, 0.f};
#pragma unroll 8
    for (int j = 0; j < 32; ++j) {
        f4 v = *(const f4*)(p + (long)j * D);
        s += v;
    }
    *(f4*)(part + ((long)(b * NCH + c)) * D + t * 4) = s;
}

// -------- scan phase B: exclusive scan over NCH chunks + total, grouped prefetch --------
__global__ void scan_offsets2(float* __restrict__ part, float* __restrict__ total) {
    int idx = blockIdx.x * 256 + threadIdx.x;   // 8192
    int b = idx >> 10, d = idx & 1023;
    float* p = part + (long)b * NCH * D + d;
    float run = 0.f;
#pragma unroll
    for (int g = 0; g < NCH / 8; ++g) {
        float v[8];
#pragma unroll
        for (int u = 0; u < 8; ++u) v[u] = p[(long)(g * 8 + u) * D];
#pragma unroll
        for (int u = 0; u < 8; ++u) { float tv = v[u]; p[(long)(g * 8 + u) * D] = run; run += tv; }
    }
    total[idx] = run;
}

// -------- scan phase C: emit ctx (bf16x4), xb (bf16x4), exact fp32 x passthrough --------
__global__ __launch_bounds__(256) void scan_ctx4(
    const float* __restrict__ x, const float* __restrict__ part,
    const float* __restrict__ total, bf16* __restrict__ ctxb,
    bf16* __restrict__ xb, float* __restrict__ outx)
{
    const int t = threadIdx.x, c = blockIdx.x, b = blockIdx.y;
    const long col = (long)t * 4;
    f4 run = *(const f4*)(part + ((long)(b * NCH + c)) * D + col);
    const f4 tot = *(const f4*)(total + (long)b * D + col);
    const long base = ((long)b * S + (long)c * 32) * D + col;
    const float invE = 1.0f / (float)(S - 1);
#pragma unroll 4
    for (int j = 0; j < 32; ++j) {
        const int s = c * 32 + j;
        f4 xv = *(const f4*)(x + base + (long)j * D);
        f4 ctx;
        if (s == 0 || s == S - 1) {
#pragma unroll
            for (int e = 0; e < 4; ++e) ctx[e] = (tot[e] - xv[e]) * invE;
        } else {
            const float invp = 1.0f / (float)s, invs = 1.0f / (float)(S - 1 - s);
#pragma unroll
            for (int e = 0; e < 4; ++e)
                ctx[e] = 0.5f * (run[e] * invp + (tot[e] - run[e] - xv[e]) * invs);
        }
        *(f4*)(outx + base + (long)j * D) = xv;
        short4v cp, xp;
#pragma unroll
        for (int e = 0; e < 4; ++e) { cp[e] = f2bfbits(ctx[e]); xp[e] = f2bfbits(xv[e]); }
        *(short4v*)((short*)ctxb + base + (long)j * D) = cp;
        *(short4v*)((short*)xb + base + (long)j * D) = xp;
        run += xv;
    }
}

// -------- 256x256-tile 8-phase GEMM, 64 KiB LDS (in-place ring-1) -> 2 blocks/CU --------
// Same datapath/swizzle/XCD-remap as the verified round-5 kernel. Change: the [2][2]
// ping-pong LDS is replaced by 4 fixed 16 KiB regions {A0,A1,B0,B1}; tile u+1's stages
// overwrite each region IN PLACE one phase after its last reader:
//   last reads: A0,B0 -> ph1; B1 -> ph2; A1 -> ph3.
//   stages:     ph2 -> A0,B0(u+1); ph3 -> B1(u+1); ph4 -> A1(u+1).
// WAR safety: a region's readers drain (lgkmcnt(0)) before their phase-end barrier; the
// stage issues after that barrier. RAW safety via the collective rule [each wave does
// s_waitcnt vmcnt(N), then s_barrier => ALL waves' loads older than the N newest landed]:
//   end-ph1 vmcnt(2) (B1 ready for ph2), end-ph2 vmcnt(4) (A1 ready for ph3),
//   end-ph4 vmcnt(4) (A0,B0 ready for next ph1). Counted, never 0; 3-phase cover each.
// LDS 64 KiB => 2 blocks/CU (16 waves/CU): cross-block overlap fills barrier stalls,
// the regime the 1-block/CU 128 KiB version could never reach (all pipes <35% busy).
__global__ __launch_bounds__(512, 4) void gemm256(
    const bf16* __restrict__ Axb, const bf16* __restrict__ Actx,
    const bf16* __restrict__ WT1, const bf16* __restrict__ WT2,
    const float* __restrict__ biasA, const float* __restrict__ biasC,
    bf16* __restrict__ O1, bf16* __restrict__ O2)
{
    __shared__ __align__(16) bf16 ldsA[2][128 * 64];   // A0, A1 (16 KiB each)
    __shared__ __align__(16) bf16 ldsB[2][128 * 64];   // B0, B1

    const int bid = blockIdx.x;
    const int xcd = bid & 7, slot = bid >> 3;
    const int gsl = slot >> 3;
    const int col_t = (gsl < 8) ? ((gsl >> 1) + ((gsl & 1) << 2)) : 8;
    const int row_t = xcd * 8 + (slot & 7);
    const int row0 = row_t * 256;
    const bool g2 = (col_t < 4);                 // heavy blocks (K=2048)
    const int col0 = (g2 ? col_t : col_t - 4) * 256;
    const int NT  = g2 ? 32 : 16;
    const int ldb = g2 ? 2048 : 1024;
    const bf16* BT = g2 ? (WT2 + (long)col0 * 2048) : (WT1 + (long)col0 * 1024);

    const int tid = threadIdx.x;
    const int w  = tid >> 6, l = tid & 63;
    const int wm = w >> 2, wn = w & 3;           // 2M x 4N waves
    const int lm = l & 15, lq = l >> 4;
    const int lr = l >> 3, cb = l & 7;
    const int ksrc = ((cb ^ lr) << 3);           // pre-swizzled source k-offset (elements)
    const int sw = lm & 7;                       // row&7 for read-side swizzle

    f32x4 acc[8][4];                             // [mh*4+i][nh*2+j]
#pragma unroll
    for (int i = 0; i < 8; ++i)
#pragma unroll
        for (int j = 0; j < 4; ++j) acc[i][j] = (f32x4){0.f, 0.f, 0.f, 0.f};

    auto stageA = [&](int t, int h) {
        if (t >= NT) return;
        const int kg = t * 64;
        const bf16* src = (kg < 1024) ? Axb : Actx;
        const int kk = kg & 1023;
        bf16* dst = &ldsA[h][0];
#pragma unroll
        for (int q = 0; q < 2; ++q) {
            const int r = w * 16 + q * 8;        // row within the 128-row half
            async_copy16(src + (long)(row0 + h * 128 + r + lr) * 1024 + kk + ksrc,
                         dst + r * 64);
        }
    };
    auto stageB = [&](int t, int h) {
        if (t >= NT) return;
        const int kg = t * 64;
        bf16* dst = &ldsB[h][0];
#pragma unroll
        for (int q = 0; q < 2; ++q) {
            const int r = w * 16 + q * 8;
            async_copy16(BT + (long)(h * 128 + r + lr) * ldb + kg + ksrc,
                         dst + r * 64);
        }
    };

    // prologue: stage tile 0 (order: A0,B0,B1,A1); wait A0,B0 (4 newest = B1,A1 in flight)
    stageA(0, 0); stageB(0, 0); stageB(0, 1); stageA(0, 1);
    asm volatile("s_waitcnt vmcnt(4)" ::: "memory");
    asm volatile("s_barrier" ::: "memory");

    short8 a[4][2];        // A frags of current mh half (i, ksub)
    short8 bbf[2][2][2];   // B frags, both halves held (nh, j, ksub)

    for (int u = 0; u < NT; ++u) {
        // ---- phase 1: read A0,B0 frags; MFMA (0,0); vmcnt(2) [B1 ready] ----
#pragma unroll
        for (int i = 0; i < 4; ++i) {
            const int ro = (wm * 64 + i * 16 + lm) * 64;
#pragma unroll
            for (int ks = 0; ks < 2; ++ks)
                a[i][ks] = *(const short8*)&ldsA[0][ro + (((ks * 4 + lq) ^ sw) << 3)];
        }
#pragma unroll
        for (int j = 0; j < 2; ++j) {
            const int ro = (wn * 32 + j * 16 + lm) * 64;
#pragma unroll
            for (int ks = 0; ks < 2; ++ks)
                bbf[0][j][ks] = *(const short8*)&ldsB[0][ro + (((ks * 4 + lq) ^ sw) << 3)];
        }
        asm volatile("s_barrier" ::: "memory");
        asm volatile("s_waitcnt lgkmcnt(0)" ::: "memory");
        __builtin_amdgcn_s_setprio(1);
#pragma unroll
        for (int i = 0; i < 4; ++i)
#pragma unroll
            for (int j = 0; j < 2; ++j)
#pragma unroll
                for (int ks = 0; ks < 2; ++ks)
                    acc[i][j] = __builtin_amdgcn_mfma_f32_16x16x32_bf16(a[i][ks], bbf[0][j][ks], acc[i][j], 0, 0, 0);
        __builtin_amdgcn_s_setprio(0);
        asm volatile("s_waitcnt vmcnt(2)" ::: "memory");
        asm volatile("s_barrier" ::: "memory");

        // ---- phase 2: read B1 frags; stage A0,B0(u+1) in place; MFMA (0,1); vmcnt(4) ----
#pragma unroll
        for (int j = 0; j < 2; ++j) {
            const int ro = (wn * 32 + j * 16 + lm) * 64;
#pragma unroll
            for (int ks = 0; ks < 2; ++ks)
                bbf[1][j][ks] = *(const short8*)&ldsB[1][ro + (((ks * 4 + lq) ^ sw) << 3)];
        }
        stageA(u + 1, 0); stageB(u + 1, 0);
        asm volatile("s_barrier" ::: "memory");
        asm volatile("s_waitcnt lgkmcnt(0)" ::: "memory");
        __builtin_amdgcn_s_setprio(1);
#pragma unroll
        for (int i = 0; i < 4; ++i)
#pragma unroll
            for (int j = 0; j < 2; ++j)
#pragma unroll
                for (int ks = 0; ks < 2; ++ks)
                    acc[i][2 + j] = __builtin_amdgcn_mfma_f32_16x16x32_bf16(a[i][ks], bbf[1][j][ks], acc[i][2 + j], 0, 0, 0);
        __builtin_amdgcn_s_setprio(0);
        asm volatile("s_waitcnt vmcnt(4)" ::: "memory");
        asm volatile("s_barrier" ::: "memory");

        // ---- phase 3: read A1 frags; stage B1(u+1) in place; MFMA (1,0) ----
#pragma unroll
        for (int i = 0; i < 4; ++i) {
            const int ro = (wm * 64 + i * 16 + lm) * 64;
#pragma unroll
            for (int ks = 0; ks < 2; ++ks)
                a[i][ks] = *(const short8*)&ldsA[1][ro + (((ks * 4 + lq) ^ sw) << 3)];
        }
        stageB(u + 1, 1);
        asm volatile("s_barrier" ::: "memory");
        asm volatile("s_waitcnt lgkmcnt(0)" ::: "memory");
        __builtin_amdgcn_s_setprio(1);
#pragma unroll
        for (int i = 0; i < 4; ++i)
#pragma unroll
            for (int j = 0; j < 2; ++j)
#pragma unroll
                for (int ks = 0; ks < 2; ++ks)
                    acc[4 + i][j] = __builtin_amdgcn_mfma_f32_16x16x32_bf16(a[i][ks], bbf[0][j][ks], acc[4 + i][j], 0, 0, 0);
        __builtin_amdgcn_s_setprio(0);
        asm volatile("s_barrier" ::: "memory");

        // ---- phase 4: stage A1(u+1) in place; MFMA (1,1) regs-only; vmcnt(4) ----
        stageA(u + 1, 1);
        __builtin_amdgcn_s_setprio(1);
#pragma unroll
        for (int i = 0; i < 4; ++i)
#pragma unroll
            for (int j = 0; j < 2; ++j)
#pragma unroll
                for (int ks = 0; ks < 2; ++ks)
                    acc[4 + i][2 + j] = __builtin_amdgcn_mfma_f32_16x16x32_bf16(a[i][ks], bbf[1][j][ks], acc[4 + i][2 + j], 0, 0, 0);
        __builtin_amdgcn_s_setprio(0);
        asm volatile("s_waitcnt vmcnt(4)" ::: "memory");
        asm volatile("s_barrier" ::: "memory");
    }

    // ---- C write: bias + optional relu, bf16 out ----
    bf16* O = g2 ? O2 : O1;
    const long ldo = g2 ? 1024 : N1;
    const float* bias = g2 ? biasC : biasA;
    const int reluN = g2 ? 0 : 768;
#pragma unroll
    for (int mh = 0; mh < 2; ++mh)
#pragma unroll
        for (int i = 0; i < 4; ++i)
#pragma unroll
            for (int nh = 0; nh < 2; ++nh)
#pragma unroll
                for (int j = 0; j < 2; ++j) {
                    const int col = col0 + nh * 128 + wn * 32 + j * 16 + lm;
                    const float bv = bias[col];
                    const bool rl = col < reluN;
                    const f32x4 av = acc[mh * 4 + i][nh * 2 + j];
#pragma unroll
                    for (int r = 0; r < 4; ++r) {
                        const int row = row0 + mh * 128 + wm * 64 + i * 16 + lq * 4 + r;
                        float v = av[r] + bv;
                        if (rl) v = fmaxf(v, 0.f);
                        O[(long)row * ldo + col] = f2bf(v);
                    }
                }
}

// -------- fused epilogue: softmax + be2 + cr2 + LN/gelu/cd2, wave per row --------
__global__ __launch_bounds__(256) void epilogue(
    const bf16* __restrict__ YB, const bf16* __restrict__ H,
    const float* __restrict__ W2T, const float* __restrict__ b2,
    const float* __restrict__ Wbe, const float* __restrict__ bbe,
    const float* __restrict__ W5, const float* __restrict__ Wcr, const float* __restrict__ bcr,
    const float* __restrict__ g, const float* __restrict__ be,
    const float* __restrict__ Wd, const float* __restrict__ bd,
    float* __restrict__ out_ct, float* __restrict__ out_enh, float* __restrict__ out_wb,
    float* __restrict__ out_rel, float* __restrict__ out_cred)
{
    const int w = threadIdx.x >> 6, l = threadIdx.x & 63;
    const long r = (long)blockIdx.x * 4 + w;
    const bf16* yrow = YB + r * N1;

    // ---- content-type softmax (cc2) ----
    short8 y1 = *(const short8*)(yrow + l * 8);
    float yv[8];
#pragma unroll
    for (int j = 0; j < 8; ++j) yv[j] = bits2f(y1[j]);
    float s5[5];
#pragma unroll
    for (int cc = 0; cc < 5; ++cc) {
        f4 wa = *(const f4*)(W2T + cc * 512 + l * 8);
        f4 wb = *(const f4*)(W2T + cc * 512 + l * 8 + 4);
        float a = 0.f;
#pragma unroll
        for (int j = 0; j < 4; ++j) a += yv[j] * wa[j];
#pragma unroll
        for (int j = 0; j < 4; ++j) a += yv[4 + j] * wb[j];
        s5[cc] = a;
    }
#pragma unroll
    for (int cc = 0; cc < 5; ++cc) s5[cc] = wsum(s5[cc]) + b2[cc];
    float mx = s5[0];
#pragma unroll
    for (int cc = 1; cc < 5; ++cc) mx = fmaxf(mx, s5[cc]);
    float ct[5]; float den = 0.f;
#pragma unroll
    for (int cc = 0; cc < 5; ++cc) { ct[cc] = expf(s5[cc] - mx); den += ct[cc]; }
    float inv = 1.f / den;
#pragma unroll
    for (int cc = 0; cc < 5; ++cc) ct[cc] *= inv;
    if (l < 5) out_ct[r * 5 + l] = ct[l];
    if (l == 0) out_rel[r] = 1.f - ct[3];

    // ---- bias path (be2) ----
    short4v y3 = *(const short4v*)(yrow + 512 + l * 4);
    f4 wv = *(const f4*)(Wbe + l * 4);
    float sb = 0.f;
#pragma unroll
    for (int j = 0; j < 4; ++j) sb += bits2f(y3[j]) * wv[j];
    sb = wsum(sb);
    if (l == 0) {
        float sig = 1.f / (1.f + expf(-(sb + bbe[0])));
        float cb = 0.1f * ct[0] + 1.0f * ct[1] + 0.8f * ct[2] + 0.3f * ct[3] + 0.5f * ct[4];
        out_wb[r] = sig * cb;
    }

    // ---- credibility (cr2, rank-5 ct correction + relu + dot) ----
    short8 y4 = *(const short8*)(yrow + 768 + l * 8);
    float corr[8] = {0, 0, 0, 0, 0, 0, 0, 0};
#pragma unroll
    for (int cc = 0; cc < 5; ++cc) {
        f4 a = *(const f4*)(W5 + cc * 512 + l * 8);
        f4 b = *(const f4*)(W5 + cc * 512 + l * 8 + 4);
#pragma unroll
        for (int j = 0; j < 4; ++j) { corr[j] += ct[cc] * a[j]; corr[4 + j] += ct[cc] * b[j]; }
    }
    f4 wca = *(const f4*)(Wcr + l * 8);
    f4 wcb = *(const f4*)(Wcr + l * 8 + 4);
    float scr = 0.f;
#pragma unroll
    for (int j = 0; j < 4; ++j) scr += fmaxf(bits2f(y4[j]) + corr[j], 0.f) * wca[j];
#pragma unroll
    for (int j = 0; j < 4; ++j) scr += fmaxf(bits2f(y4[4 + j]) + corr[4 + j], 0.f) * wcb[j];
    scr = wsum(scr);
    if (l == 0) out_cred[r] = 1.f / (1.f + expf(-(scr + bcr[0])));

    // ---- LN + gelu + cd2 (lane owns elements l*8 + c*512, c=0,1) ----
    const bf16* hrow = H + r * 1024;
    float v[16];
    float sum = 0.f, sum2 = 0.f;
#pragma unroll
    for (int c = 0; c < 2; ++c) {
        short8 hh = *(const short8*)(hrow + c * 512 + l * 8);
#pragma unroll
        for (int j = 0; j < 8; ++j) {
            float f = bits2f(hh[j]);
            v[c * 8 + j] = f;
            sum += f; sum2 += f * f;
        }
    }
    sum = wsum(sum);
    sum2 = wsum(sum2);
    float mu = sum * (1.f / 1024.f);
    float var = sum2 * (1.f / 1024.f) - mu * mu;
    float rstd = rsqrtf(var + 1e-5f);
    float dot = 0.f;
#pragma unroll
    for (int c = 0; c < 2; ++c) {
        int base = c * 512 + l * 8;
        f4 ga = *(const f4*)(g + base),  gb = *(const f4*)(g + base + 4);
        f4 ba = *(const f4*)(be + base), bb = *(const f4*)(be + base + 4);
        f4 wa = *(const f4*)(Wd + base), wb = *(const f4*)(Wd + base + 4);
#pragma unroll
        for (int j = 0; j < 4; ++j) {
            float hn = (v[c * 8 + j] - mu) * rstd * ga[j] + ba[j];
            float ge = 0.5f * hn * (1.f + erff(hn * 0.70710678118654752f));
            dot += ge * wa[j];
            float hn2 = (v[c * 8 + 4 + j] - mu) * rstd * gb[j] + bb[j];
            float ge2 = 0.5f * hn2 * (1.f + erff(hn2 * 0.70710678118654752f));
            dot += ge2 * wb[j];
        }
    }
    dot = wsum(dot);
    if (l == 0) {
        float contr = 1.f / (1.f + expf(-(dot + bd[0])));
        out_enh[r] = fmaxf(contr, ct[2]);
    }
}

extern "C" void kernel_launch(void* const* d_in, const int* in_sizes, int n_in,
                              void* d_out, int out_size, void* d_ws, size_t ws_size,
                              hipStream_t stream) {
    const float* x      = (const float*)d_in[0];
    const float* W_cc1  = (const float*)d_in[1];
    const float* b_cc1  = (const float*)d_in[2];
    const float* W_cc2  = (const float*)d_in[3];
    const float* b_cc2  = (const float*)d_in[4];
    const float* W_cd1  = (const float*)d_in[5];
    const float* b_cd1  = (const float*)d_in[6];
    const float* g_ln   = (const float*)d_in[7];
    const float* be_ln  = (const float*)d_in[8];
    const float* W_cd2  = (const float*)d_in[9];
    const float* b_cd2  = (const float*)d_in[10];
    const float* W_be1  = (const float*)d_in[11];
    const float* b_be1  = (const float*)d_in[12];
    const float* W_be2  = (const float*)d_in[13];
    const float* b_be2  = (const float*)d_in[14];
    const float* W_cr1  = (const float*)d_in[15];
    const float* b_cr1  = (const float*)d_in[16];
    const float* W_cr2  = (const float*)d_in[17];
    const float* b_cr2  = (const float*)d_in[18];

    float* out = (float*)d_out;
    float* out_x    = out;
    float* out_ct   = out_x + (long)ROWS * D;
    float* out_enh  = out_ct + ROWS * 5;
    float* out_wb   = out_enh + ROWS;
    float* out_rel  = out_wb + ROWS;
    float* out_cred = out_rel + ROWS;

    char* cur = (char*)d_ws;
    auto alloc = [&](size_t bytes) { char* p = cur; cur += (bytes + 255) & ~(size_t)255; return p; };

    bf16* WT1    = (bf16*)alloc((size_t)N1 * 1024 * 2);     // [1280][1024]
    bf16* WT2    = (bf16*)alloc((size_t)1024 * 2048 * 2);   // [1024][2048] cd1 full
    float* W2T   = (float*)alloc((size_t)5 * 512 * 4);
    float* biasA = (float*)alloc((size_t)N1 * 4);
    bf16* xb     = (bf16*)alloc((size_t)ROWS * 1024 * 2);
    bf16* ctxb   = (bf16*)alloc((size_t)ROWS * 1024 * 2);
    bf16* YB     = (bf16*)alloc((size_t)ROWS * N1 * 2);     // 40 MB
    bf16* Hbuf   = (bf16*)alloc((size_t)ROWS * 1024 * 2);   // 32 MB
    float* part  = (float*)alloc((size_t)Bb * NCH * 1024 * 4);
    float* totl  = (float*)alloc((size_t)Bb * 1024 * 4);

    // one prep kernel: all weight transposes + W2T + bias concat
    prep_all<<<833, 256, 0, stream>>>(W_cc1, W_be1, W_cr1, W_cd1, W_cc2,
                                      b_cc1, b_be1, b_cr1, WT1, WT2, W2T, biasA);

    // ctx scan (round-1 config: 32-row chunks, float4 lanes)
    scan_partial4<<<dim3(NCH, Bb), 256, 0, stream>>>(x, part);
    scan_offsets2<<<32, 256, 0, stream>>>(part, totl);
    scan_ctx4<<<dim3(NCH, Bb), 256, 0, stream>>>(x, part, totl, ctxb, xb, out_x);

    // 256x256 8-phase GEMM, 64 KiB LDS (2 blocks/CU), XCD-strip remap:
    //   g2 cols (K=2048) -> Hbuf; g1 cols (K=1024) -> YB
    gemm256<<<dim3(9 * MT2), 512, 0, stream>>>(
        xb, ctxb, WT1, WT2, biasA, b_cd1, YB, Hbuf);

    // fused epilogue (softmax, be2, cr2, LN+gelu+cd2)
    epilogue<<<ROWS / 4, 256, 0, stream>>>(
        YB, Hbuf, W2T, b_cc2, W_be2, b_be2,
        W_cr1 + (long)1024 * 512, W_cr2, b_cr2,
        g_ln, be_ln, W_cd2, b_cd2,
        out_ct, out_enh, out_wb, out_rel, out_cred);

    (void)in_sizes; (void)n_in; (void)out_size; (void)ws_size;
}

// Round 7
// 351.736 us; speedup vs baseline: 3.1758x; 3.1758x over previous
//
#include <hip/hip_runtime.h>
#include <hip/hip_bf16.h>
#include <cstdint>

typedef __hip_bfloat16 bf16;
using short8 = __attribute__((ext_vector_type(8))) short;
using short4v = __attribute__((ext_vector_type(4))) short;
using f32x4  = __attribute__((ext_vector_type(4))) float;
using f4     = __attribute__((ext_vector_type(4))) float;

#define DEV __device__ __forceinline__

static constexpr int Bb = 8;
static constexpr int S  = 2048;
static constexpr int D  = 1024;
static constexpr long ROWS = (long)Bb * S;   // 16384
static constexpr int N1 = 1280;              // 512(cc1) + 256(be1) + 512(cr1-x)
static constexpr int NCH = 64;               // scan chunks (32 rows each)
static constexpr int MT2 = 64;               // 256-row tiles = ROWS/256

DEV void async_copy16(const void* g, void* l) {
    __builtin_amdgcn_global_load_lds((const __attribute__((address_space(1))) void*)g,
                                     (__attribute__((address_space(3))) void*)l,
                                     16, 0, 0);
}

DEV float wsum(float v) {
#pragma unroll
    for (int off = 32; off > 0; off >>= 1) v += __shfl_xor(v, off, 64);
    return v;
}

DEV float bf2f(bf16 x) { return __bfloat162float(x); }
DEV bf16  f2bf(float x) { return __float2bfloat16(x); }
DEV short f2bfbits(float v) { bf16 h = f2bf(v); short s; __builtin_memcpy(&s, &h, 2); return s; }
DEV float bits2f(short s) {
    unsigned u = ((unsigned)(unsigned short)s) << 16;
    float f; __builtin_memcpy(&f, &u, 4); return f;
}

// -------- single prep kernel: 4 tiled transposes (fp32->bf16 B^T) + W2T + bias concat ------
// tiles: [0,128) cc1 | [128,192) be1 | [192,320) cr1 | [320,832) cd1 | 832 small stuff
__global__ __launch_bounds__(256) void prep_all(
    const float* __restrict__ Wcc1, const float* __restrict__ Wbe1,
    const float* __restrict__ Wcr1, const float* __restrict__ Wcd1,
    const float* __restrict__ Wcc2,
    const float* __restrict__ b1, const float* __restrict__ b2, const float* __restrict__ b3,
    bf16* __restrict__ WT1, bf16* __restrict__ WT2,
    float* __restrict__ W2T, float* __restrict__ biasA)
{
    const int bid = blockIdx.x, t = threadIdx.x;
    if (bid == 832) {
        for (int i = t; i < 2560; i += 256) {
            int cc = i >> 9, n = i & 511;
            W2T[i] = Wcc2[(long)n * 5 + cc];
        }
        for (int i = t; i < N1; i += 256) {
            float v;
            if (i < 512)       v = b1[i];
            else if (i < 768)  v = b2[i - 512];
            else               v = b3[i - 768];
            biasA[i] = v;
        }
        return;
    }
    const float* W; int ldw; bf16* dst; long dstLd, dstOff; int nt, kt;
    if (bid < 128)      { W = Wcc1; ldw = 512;  dst = WT1; dstLd = 1024; dstOff = 0;
                          nt = bid & 7; kt = bid >> 3; }
    else if (bid < 192) { W = Wbe1; ldw = 256;  dst = WT1; dstLd = 1024; dstOff = (long)512 * 1024;
                          int lb = bid - 128; nt = lb & 3; kt = lb >> 2; }
    else if (bid < 320) { W = Wcr1; ldw = 512;  dst = WT1; dstLd = 1024; dstOff = (long)768 * 1024;
                          int lb = bid - 192; nt = lb & 7; kt = lb >> 3; }
    else                { W = Wcd1; ldw = 1024; dst = WT2; dstLd = 2048; dstOff = 0;
                          int lb = bid - 320; nt = lb & 15; kt = lb >> 4; }

    __shared__ float tile[64][65];
    const int tx = t & 63, ty = t >> 6;
    const int k64 = kt * 64, n64 = nt * 64;
#pragma unroll
    for (int p = 0; p < 16; ++p) {
        int k = ty * 16 + p;
        tile[k][tx] = W[(long)(k64 + k) * ldw + n64 + tx];
    }
    __syncthreads();
#pragma unroll
    for (int p = 0; p < 16; ++p) {
        int n = ty * 16 + p;
        dst[dstOff + (long)(n64 + n) * dstLd + k64 + tx] = f2bf(tile[tx][n]);
    }
}

// -------- scan phase A: per-chunk partial sums, float4 lanes (chunk = 32 rows) --------
__global__ __launch_bounds__(256) void scan_partial4(const float* __restrict__ x,
                                                     float* __restrict__ part) {
    const int t = threadIdx.x, c = blockIdx.x, b = blockIdx.y;
    const float* p = x + ((long)b * S + (long)c * 32) * D + t * 4;
    f4 s = {0.f, 0.f, 0.f, 0.f};
#pragma unroll 8
    for (int j = 0; j < 32; ++j) {
        f4 v = *(const f4*)(p + (long)j * D);
        s += v;
    }
    *(f4*)(part + ((long)(b * NCH + c)) * D + t * 4) = s;
}

// -------- scan phase B: exclusive scan over NCH chunks + total, grouped prefetch --------
__global__ void scan_offsets2(float* __restrict__ part, float* __restrict__ total) {
    int idx = blockIdx.x * 256 + threadIdx.x;   // 8192
    int b = idx >> 10, d = idx & 1023;
    float* p = part + (long)b * NCH * D + d;
    float run = 0.f;
#pragma unroll
    for (int g = 0; g < NCH / 8; ++g) {
        float v[8];
#pragma unroll
        for (int u = 0; u < 8; ++u) v[u] = p[(long)(g * 8 + u) * D];
#pragma unroll
        for (int u = 0; u < 8; ++u) { float tv = v[u]; p[(long)(g * 8 + u) * D] = run; run += tv; }
    }
    total[idx] = run;
}

// -------- scan phase C: emit ctx (bf16x4), xb (bf16x4), exact fp32 x passthrough --------
__global__ __launch_bounds__(256) void scan_ctx4(
    const float* __restrict__ x, const float* __restrict__ part,
    const float* __restrict__ total, bf16* __restrict__ ctxb,
    bf16* __restrict__ xb, float* __restrict__ outx)
{
    const int t = threadIdx.x, c = blockIdx.x, b = blockIdx.y;
    const long col = (long)t * 4;
    f4 run = *(const f4*)(part + ((long)(b * NCH + c)) * D + col);
    const f4 tot = *(const f4*)(total + (long)b * D + col);
    const long base = ((long)b * S + (long)c * 32) * D + col;
    const float invE = 1.0f / (float)(S - 1);
#pragma unroll 4
    for (int j = 0; j < 32; ++j) {
        const int s = c * 32 + j;
        f4 xv = *(const f4*)(x + base + (long)j * D);
        f4 ctx;
        if (s == 0 || s == S - 1) {
#pragma unroll
            for (int e = 0; e < 4; ++e) ctx[e] = (tot[e] - xv[e]) * invE;
        } else {
            const float invp = 1.0f / (float)s, invs = 1.0f / (float)(S - 1 - s);
#pragma unroll
            for (int e = 0; e < 4; ++e)
                ctx[e] = 0.5f * (run[e] * invp + (tot[e] - run[e] - xv[e]) * invs);
        }
        *(f4*)(outx + base + (long)j * D) = xv;
        short4v cp, xp;
#pragma unroll
        for (int e = 0; e < 4; ++e) { cp[e] = f2bfbits(ctx[e]); xp[e] = f2bfbits(xv[e]); }
        *(short4v*)((short*)ctxb + base + (long)j * D) = cp;
        *(short4v*)((short*)xb + base + (long)j * D) = xp;
        run += xv;
    }
}

// -------- 256x256-tile 8-phase MFMA GEMM + XCD-strip block remap (round-5, best) --------
// Datapath identical to the verified round-1 kernel; XCD-strip bid remap (round 5, best
// measured 138.5us). launch_bounds second arg dropped: LDS (128 KiB) already caps
// occupancy at 1 block/CU, so unclamping the register allocator (>128 VGPR allowed)
// can only add scheduling headroom, never reduce occupancy. (Round-6 lesson: a forced
// 64-VGPR cap spills the 128-reg accumulator -> 2.2 GB scratch traffic, 6.5x slowdown.)
__global__ __launch_bounds__(512) void gemm256(
    const bf16* __restrict__ Axb, const bf16* __restrict__ Actx,
    const bf16* __restrict__ WT1, const bf16* __restrict__ WT2,
    const float* __restrict__ biasA, const float* __restrict__ biasC,
    bf16* __restrict__ O1, bf16* __restrict__ O2)
{
    __shared__ __align__(16) bf16 ldsA[2][2][128 * 64];
    __shared__ __align__(16) bf16 ldsB[2][2][128 * 64];

    const int bid = blockIdx.x;
    const int xcd = bid & 7, slot = bid >> 3;
    const int gsl = slot >> 3;
    const int col_t = (gsl < 8) ? ((gsl >> 1) + ((gsl & 1) << 2)) : 8;
    const int row_t = xcd * 8 + (slot & 7);
    const int row0 = row_t * 256;
    const bool g2 = (col_t < 4);                 // heavy blocks (K=2048)
    const int col0 = (g2 ? col_t : col_t - 4) * 256;
    const int NT  = g2 ? 32 : 16;
    const int ldb = g2 ? 2048 : 1024;
    const bf16* BT = g2 ? (WT2 + (long)col0 * 2048) : (WT1 + (long)col0 * 1024);

    const int tid = threadIdx.x;
    const int w  = tid >> 6, l = tid & 63;
    const int wm = w >> 2, wn = w & 3;           // 2M x 4N waves
    const int lm = l & 15, lq = l >> 4;
    const int lr = l >> 3, cb = l & 7;
    const int ksrc = ((cb ^ lr) << 3);           // pre-swizzled source k-offset (elements)
    const int sw = lm & 7;                       // row&7 for read-side swizzle

    f32x4 acc[8][4];                             // [mh*4+i][nh*2+j]
#pragma unroll
    for (int i = 0; i < 8; ++i)
#pragma unroll
        for (int j = 0; j < 4; ++j) acc[i][j] = (f32x4){0.f, 0.f, 0.f, 0.f};

    auto stageA = [&](int t, int h) {
        if (t >= NT) return;
        const int kg = t * 64;
        const bf16* src = (kg < 1024) ? Axb : Actx;
        const int kk = kg & 1023;
        bf16* dst = &ldsA[t & 1][h][0];
#pragma unroll
        for (int q = 0; q < 2; ++q) {
            const int r = w * 16 + q * 8;        // row within the 128-row half
            async_copy16(src + (long)(row0 + h * 128 + r + lr) * 1024 + kk + ksrc,
                         dst + r * 64);
        }
    };
    auto stageB = [&](int t, int h) {
        if (t >= NT) return;
        const int kg = t * 64;
        bf16* dst = &ldsB[t & 1][h][0];
#pragma unroll
        for (int q = 0; q < 2; ++q) {
            const int r = w * 16 + q * 8;
            async_copy16(BT + (long)(h * 128 + r + lr) * ldb + kg + ksrc,
                         dst + r * 64);
        }
    };

    // prologue: tile 0 fully + tile 1 (A0,B0); leave 4 loads in flight
    stageA(0, 0); stageB(0, 0); stageB(0, 1); stageA(0, 1);
    stageA(1, 0); stageB(1, 0);
    asm volatile("s_waitcnt vmcnt(4)" ::: "memory");
    asm volatile("s_barrier" ::: "memory");

    short8 a[4][2];        // A frags of current mh half (i, ksub)
    short8 bbf[2][2][2];   // B frags, both halves held (nh, j, ksub)

    for (int u = 0; u < NT; ++u) {
        const bf16* bufA0 = &ldsA[u & 1][0][0];
        const bf16* bufA1 = &ldsA[u & 1][1][0];
        const bf16* bufB0 = &ldsB[u & 1][0][0];
        const bf16* bufB1 = &ldsB[u & 1][1][0];

        // ---- phase 1: quadrant (0,0) : read A0 + B0, stage (u+1).B1 ----
#pragma unroll
        for (int i = 0; i < 4; ++i) {
            const int ro = (wm * 64 + i * 16 + lm) * 64;
#pragma unroll
            for (int ks = 0; ks < 2; ++ks)
                a[i][ks] = *(const short8*)&bufA0[ro + (((ks * 4 + lq) ^ sw) << 3)];
        }
#pragma unroll
        for (int j = 0; j < 2; ++j) {
            const int ro = (wn * 32 + j * 16 + lm) * 64;
#pragma unroll
            for (int ks = 0; ks < 2; ++ks)
                bbf[0][j][ks] = *(const short8*)&bufB0[ro + (((ks * 4 + lq) ^ sw) << 3)];
        }
        stageB(u + 1, 1);
        asm volatile("s_barrier" ::: "memory");
        asm volatile("s_waitcnt lgkmcnt(0)" ::: "memory");
        __builtin_amdgcn_s_setprio(1);
#pragma unroll
        for (int i = 0; i < 4; ++i)
#pragma unroll
            for (int j = 0; j < 2; ++j)
#pragma unroll
                for (int ks = 0; ks < 2; ++ks)
                    acc[i][j] = __builtin_amdgcn_mfma_f32_16x16x32_bf16(a[i][ks], bbf[0][j][ks], acc[i][j], 0, 0, 0);
        __builtin_amdgcn_s_setprio(0);
        asm volatile("s_barrier" ::: "memory");

        // ---- phase 2: quadrant (0,1) : read B1, stage (u+1).A1 ----
#pragma unroll
        for (int j = 0; j < 2; ++j) {
            const int ro = (wn * 32 + j * 16 + lm) * 64;
#pragma unroll
            for (int ks = 0; ks < 2; ++ks)
                bbf[1][j][ks] = *(const short8*)&bufB1[ro + (((ks * 4 + lq) ^ sw) << 3)];
        }
        stageA(u + 1, 1);
        asm volatile("s_barrier" ::: "memory");
        asm volatile("s_waitcnt lgkmcnt(0)" ::: "memory");
        __builtin_amdgcn_s_setprio(1);
#pragma unroll
        for (int i = 0; i < 4; ++i)
#pragma unroll
            for (int j = 0; j < 2; ++j)
#pragma unroll
                for (int ks = 0; ks < 2; ++ks)
                    acc[i][2 + j] = __builtin_amdgcn_mfma_f32_16x16x32_bf16(a[i][ks], bbf[1][j][ks], acc[i][2 + j], 0, 0, 0);
        __builtin_amdgcn_s_setprio(0);
        asm volatile("s_barrier" ::: "memory");

        // ---- phase 3: quadrant (1,0) : read A1, stage (u+2).A0 ----
#pragma unroll
        for (int i = 0; i < 4; ++i) {
            const int ro = (wm * 64 + i * 16 + lm) * 64;
#pragma unroll
            for (int ks = 0; ks < 2; ++ks)
                a[i][ks] = *(const short8*)&bufA1[ro + (((ks * 4 + lq) ^ sw) << 3)];
        }
        stageA(u + 2, 0);
        asm volatile("s_barrier" ::: "memory");
        asm volatile("s_waitcnt lgkmcnt(0)" ::: "memory");
        __builtin_amdgcn_s_setprio(1);
#pragma unroll
        for (int i = 0; i < 4; ++i)
#pragma unroll
            for (int j = 0; j < 2; ++j)
#pragma unroll
                for (int ks = 0; ks < 2; ++ks)
                    acc[4 + i][j] = __builtin_amdgcn_mfma_f32_16x16x32_bf16(a[i][ks], bbf[0][j][ks], acc[4 + i][j], 0, 0, 0);
        __builtin_amdgcn_s_setprio(0);
        asm volatile("s_barrier" ::: "memory");

        // ---- phase 4: quadrant (1,1) : stage (u+2).B0, counted vmcnt ----
        stageB(u + 2, 0);
        asm volatile("s_barrier" ::: "memory");
        asm volatile("s_waitcnt lgkmcnt(0)" ::: "memory");
        __builtin_amdgcn_s_setprio(1);
#pragma unroll
        for (int i = 0; i < 4; ++i)
#pragma unroll
            for (int j = 0; j < 2; ++j)
#pragma unroll
                for (int ks = 0; ks < 2; ++ks)
                    acc[4 + i][2 + j] = __builtin_amdgcn_mfma_f32_16x16x32_bf16(a[i][ks], bbf[1][j][ks], acc[4 + i][2 + j], 0, 0, 0);
        __builtin_amdgcn_s_setprio(0);
        if (u + 2 < NT) asm volatile("s_waitcnt vmcnt(4)" ::: "memory");
        else            asm volatile("s_waitcnt vmcnt(0)" ::: "memory");
        asm volatile("s_barrier" ::: "memory");
    }

    // ---- C write: bias + optional relu, bf16 out ----
    bf16* O = g2 ? O2 : O1;
    const long ldo = g2 ? 1024 : N1;
    const float* bias = g2 ? biasC : biasA;
    const int reluN = g2 ? 0 : 768;
#pragma unroll
    for (int mh = 0; mh < 2; ++mh)
#pragma unroll
        for (int i = 0; i < 4; ++i)
#pragma unroll
            for (int nh = 0; nh < 2; ++nh)
#pragma unroll
                for (int j = 0; j < 2; ++j) {
                    const int col = col0 + nh * 128 + wn * 32 + j * 16 + lm;
                    const float bv = bias[col];
                    const bool rl = col < reluN;
                    const f32x4 av = acc[mh * 4 + i][nh * 2 + j];
#pragma unroll
                    for (int r = 0; r < 4; ++r) {
                        const int row = row0 + mh * 128 + wm * 64 + i * 16 + lq * 4 + r;
                        float v = av[r] + bv;
                        if (rl) v = fmaxf(v, 0.f);
                        O[(long)row * ldo + col] = f2bf(v);
                    }
                }
}

// -------- fused epilogue: softmax + be2 + cr2 + LN/gelu/cd2, wave per row --------
__global__ __launch_bounds__(256) void epilogue(
    const bf16* __restrict__ YB, const bf16* __restrict__ H,
    const float* __restrict__ W2T, const float* __restrict__ b2,
    const float* __restrict__ Wbe, const float* __restrict__ bbe,
    const float* __restrict__ W5, const float* __restrict__ Wcr, const float* __restrict__ bcr,
    const float* __restrict__ g, const float* __restrict__ be,
    const float* __restrict__ Wd, const float* __restrict__ bd,
    float* __restrict__ out_ct, float* __restrict__ out_enh, float* __restrict__ out_wb,
    float* __restrict__ out_rel, float* __restrict__ out_cred)
{
    const int w = threadIdx.x >> 6, l = threadIdx.x & 63;
    const long r = (long)blockIdx.x * 4 + w;
    const bf16* yrow = YB + r * N1;

    // ---- content-type softmax (cc2) ----
    short8 y1 = *(const short8*)(yrow + l * 8);
    float yv[8];
#pragma unroll
    for (int j = 0; j < 8; ++j) yv[j] = bits2f(y1[j]);
    float s5[5];
#pragma unroll
    for (int cc = 0; cc < 5; ++cc) {
        f4 wa = *(const f4*)(W2T + cc * 512 + l * 8);
        f4 wb = *(const f4*)(W2T + cc * 512 + l * 8 + 4);
        float a = 0.f;
#pragma unroll
        for (int j = 0; j < 4; ++j) a += yv[j] * wa[j];
#pragma unroll
        for (int j = 0; j < 4; ++j) a += yv[4 + j] * wb[j];
        s5[cc] = a;
    }
#pragma unroll
    for (int cc = 0; cc < 5; ++cc) s5[cc] = wsum(s5[cc]) + b2[cc];
    float mx = s5[0];
#pragma unroll
    for (int cc = 1; cc < 5; ++cc) mx = fmaxf(mx, s5[cc]);
    float ct[5]; float den = 0.f;
#pragma unroll
    for (int cc = 0; cc < 5; ++cc) { ct[cc] = expf(s5[cc] - mx); den += ct[cc]; }
    float inv = 1.f / den;
#pragma unroll
    for (int cc = 0; cc < 5; ++cc) ct[cc] *= inv;
    if (l < 5) out_ct[r * 5 + l] = ct[l];
    if (l == 0) out_rel[r] = 1.f - ct[3];

    // ---- bias path (be2) ----
    short4v y3 = *(const short4v*)(yrow + 512 + l * 4);
    f4 wv = *(const f4*)(Wbe + l * 4);
    float sb = 0.f;
#pragma unroll
    for (int j = 0; j < 4; ++j) sb += bits2f(y3[j]) * wv[j];
    sb = wsum(sb);
    if (l == 0) {
        float sig = 1.f / (1.f + expf(-(sb + bbe[0])));
        float cb = 0.1f * ct[0] + 1.0f * ct[1] + 0.8f * ct[2] + 0.3f * ct[3] + 0.5f * ct[4];
        out_wb[r] = sig * cb;
    }

    // ---- credibility (cr2, rank-5 ct correction + relu + dot) ----
    short8 y4 = *(const short8*)(yrow + 768 + l * 8);
    float corr[8] = {0, 0, 0, 0, 0, 0, 0, 0};
#pragma unroll
    for (int cc = 0; cc < 5; ++cc) {
        f4 a = *(const f4*)(W5 + cc * 512 + l * 8);
        f4 b = *(const f4*)(W5 + cc * 512 + l * 8 + 4);
#pragma unroll
        for (int j = 0; j < 4; ++j) { corr[j] += ct[cc] * a[j]; corr[4 + j] += ct[cc] * b[j]; }
    }
    f4 wca = *(const f4*)(Wcr + l * 8);
    f4 wcb = *(const f4*)(Wcr + l * 8 + 4);
    float scr = 0.f;
#pragma unroll
    for (int j = 0; j < 4; ++j) scr += fmaxf(bits2f(y4[j]) + corr[j], 0.f) * wca[j];
#pragma unroll
    for (int j = 0; j < 4; ++j) scr += fmaxf(bits2f(y4[4 + j]) + corr[4 + j], 0.f) * wcb[j];
    scr = wsum(scr);
    if (l == 0) out_cred[r] = 1.f / (1.f + expf(-(scr + bcr[0])));

    // ---- LN + gelu + cd2 (lane owns elements l*8 + c*512, c=0,1) ----
    const bf16* hrow = H + r * 1024;
    float v[16];
    float sum = 0.f, sum2 = 0.f;
#pragma unroll
    for (int c = 0; c < 2; ++c) {
        short8 hh = *(const short8*)(hrow + c * 512 + l * 8);
#pragma unroll
        for (int j = 0; j < 8; ++j) {
            float f = bits2f(hh[j]);
            v[c * 8 + j] = f;
            sum += f; sum2 += f * f;
        }
    }
    sum = wsum(sum);
    sum2 = wsum(sum2);
    float mu = sum * (1.f / 1024.f);
    float var = sum2 * (1.f / 1024.f) - mu * mu;
    float rstd = rsqrtf(var + 1e-5f);
    float dot = 0.f;
#pragma unroll
    for (int c = 0; c < 2; ++c) {
        int base = c * 512 + l * 8;
        f4 ga = *(const f4*)(g + base),  gb = *(const f4*)(g + base + 4);
        f4 ba = *(const f4*)(be + base), bb = *(const f4*)(be + base + 4);
        f4 wa = *(const f4*)(Wd + base), wb = *(const f4*)(Wd + base + 4);
#pragma unroll
        for (int j = 0; j < 4; ++j) {
            float hn = (v[c * 8 + j] - mu) * rstd * ga[j] + ba[j];
            float ge = 0.5f * hn * (1.f + erff(hn * 0.70710678118654752f));
            dot += ge * wa[j];
            float hn2 = (v[c * 8 + 4 + j] - mu) * rstd * gb[j] + bb[j];
            float ge2 = 0.5f * hn2 * (1.f + erff(hn2 * 0.70710678118654752f));
            dot += ge2 * wb[j];
        }
    }
    dot = wsum(dot);
    if (l == 0) {
        float contr = 1.f / (1.f + expf(-(dot + bd[0])));
        out_enh[r] = fmaxf(contr, ct[2]);
    }
}

extern "C" void kernel_launch(void* const* d_in, const int* in_sizes, int n_in,
                              void* d_out, int out_size, void* d_ws, size_t ws_size,
                              hipStream_t stream) {
    const float* x      = (const float*)d_in[0];
    const float* W_cc1  = (const float*)d_in[1];
    const float* b_cc1  = (const float*)d_in[2];
    const float* W_cc2  = (const float*)d_in[3];
    const float* b_cc2  = (const float*)d_in[4];
    const float* W_cd1  = (const float*)d_in[5];
    const float* b_cd1  = (const float*)d_in[6];
    const float* g_ln   = (const float*)d_in[7];
    const float* be_ln  = (const float*)d_in[8];
    const float* W_cd2  = (const float*)d_in[9];
    const float* b_cd2  = (const float*)d_in[10];
    const float* W_be1  = (const float*)d_in[11];
    const float* b_be1  = (const float*)d_in[12];
    const float* W_be2  = (const float*)d_in[13];
    const float* b_be2  = (const float*)d_in[14];
    const float* W_cr1  = (const float*)d_in[15];
    const float* b_cr1  = (const float*)d_in[16];
    const float* W_cr2  = (const float*)d_in[17];
    const float* b_cr2  = (const float*)d_in[18];

    float* out = (float*)d_out;
    float* out_x    = out;
    float* out_ct   = out_x + (long)ROWS * D;
    float* out_enh  = out_ct + ROWS * 5;
    float* out_wb   = out_enh + ROWS;
    float* out_rel  = out_wb + ROWS;
    float* out_cred = out_rel + ROWS;

    char* cur = (char*)d_ws;
    auto alloc = [&](size_t bytes) { char* p = cur; cur += (bytes + 255) & ~(size_t)255; return p; };

    bf16* WT1    = (bf16*)alloc((size_t)N1 * 1024 * 2);     // [1280][1024]
    bf16* WT2    = (bf16*)alloc((size_t)1024 * 2048 * 2);   // [1024][2048] cd1 full
    float* W2T   = (float*)alloc((size_t)5 * 512 * 4);
    float* biasA = (float*)alloc((size_t)N1 * 4);
    bf16* xb     = (bf16*)alloc((size_t)ROWS * 1024 * 2);
    bf16* ctxb   = (bf16*)alloc((size_t)ROWS * 1024 * 2);
    bf16* YB     = (bf16*)alloc((size_t)ROWS * N1 * 2);     // 40 MB
    bf16* Hbuf   = (bf16*)alloc((size_t)ROWS * 1024 * 2);   // 32 MB
    float* part  = (float*)alloc((size_t)Bb * NCH * 1024 * 4);
    float* totl  = (float*)alloc((size_t)Bb * 1024 * 4);

    // one prep kernel: all weight transposes + W2T + bias concat
    prep_all<<<833, 256, 0, stream>>>(W_cc1, W_be1, W_cr1, W_cd1, W_cc2,
                                      b_cc1, b_be1, b_cr1, WT1, WT2, W2T, biasA);

    // ctx scan (round-1 config: 32-row chunks, float4 lanes)
    scan_partial4<<<dim3(NCH, Bb), 256, 0, stream>>>(x, part);
    scan_offsets2<<<32, 256, 0, stream>>>(part, totl);
    scan_ctx4<<<dim3(NCH, Bb), 256, 0, stream>>>(x, part, totl, ctxb, xb, out_x);

    // 256x256 8-phase GEMM (round-5 best) with XCD-strip remap:
    //   g2 cols (K=2048) -> Hbuf; g1 cols (K=1024) -> YB
    gemm256<<<dim3(9 * MT2), 512, 0, stream>>>(
        xb, ctxb, WT1, WT2, biasA, b_cd1, YB, Hbuf);

    // fused epilogue (softmax, be2, cr2, LN+gelu+cd2)
    epilogue<<<ROWS / 4, 256, 0, stream>>>(
        YB, Hbuf, W2T, b_cc2, W_be2, b_be2,
        W_cr1 + (long)1024 * 512, W_cr2, b_cr2,
        g_ln, be_ln, W_cd2, b_cd2,
        out_ct, out_enh, out_wb, out_rel, out_cred);

    (void)in_sizes; (void)n_in; (void)out_size; (void)ws_size;
}

// Round 8
// 342.507 us; speedup vs baseline: 3.2614x; 1.0269x over previous
//
#include <hip/hip_runtime.h>
#include <hip/hip_bf16.h>
#include <cstdint>

typedef __hip_bfloat16 bf16;
using short8 = __attribute__((ext_vector_type(8))) short;
using short4v = __attribute__((ext_vector_type(4))) short;
using f32x4  = __attribute__((ext_vector_type(4))) float;
using f4     = __attribute__((ext_vector_type(4))) float;

#define DEV __device__ __forceinline__

static constexpr int Bb = 8;
static constexpr int S  = 2048;
static constexpr int D  = 1024;
static constexpr long ROWS = (long)Bb * S;   // 16384
static constexpr int N1 = 1280;              // 512(cc1) + 256(be1) + 512(cr1-x)
static constexpr int NCH = 64;               // scan chunks (32 rows each)
static constexpr int MT2 = 64;               // 256-row tiles = ROWS/256

DEV void async_copy16(const void* g, void* l) {
    __builtin_amdgcn_global_load_lds((const __attribute__((address_space(1))) void*)g,
                                     (__attribute__((address_space(3))) void*)l,
                                     16, 0, 0);
}

DEV float wsum(float v) {
#pragma unroll
    for (int off = 32; off > 0; off >>= 1) v += __shfl_xor(v, off, 64);
    return v;
}

DEV float bf2f(bf16 x) { return __bfloat162float(x); }
DEV bf16  f2bf(float x) { return __float2bfloat16(x); }
DEV short f2bfbits(float v) { bf16 h = f2bf(v); short s; __builtin_memcpy(&s, &h, 2); return s; }
DEV float bits2f(short s) {
    unsigned u = ((unsigned)(unsigned short)s) << 16;
    float f; __builtin_memcpy(&f, &u, 4); return f;
}

// -------- merged prep + scan-A kernel --------
// blocks [0,833): weight transposes (fp32->bf16 B^T) + W2T + bias concat (independent work)
// blocks [833,1345): scan phase A -- per-chunk partial sums of x; ALSO emits the exact
// fp32 x passthrough (outx) and the bf16 xb conversion (both need only x, which this
// pass already streams). Co-dispatch fills the machine and removes one launch gap;
// moving the 64+32 MB of outx/xb writes here balances the two big streaming kernels.
__global__ __launch_bounds__(256) void prep_scanA(
    const float* __restrict__ Wcc1, const float* __restrict__ Wbe1,
    const float* __restrict__ Wcr1, const float* __restrict__ Wcd1,
    const float* __restrict__ Wcc2,
    const float* __restrict__ b1, const float* __restrict__ b2, const float* __restrict__ b3,
    bf16* __restrict__ WT1, bf16* __restrict__ WT2,
    float* __restrict__ W2T, float* __restrict__ biasA,
    const float* __restrict__ x, float* __restrict__ part,
    float* __restrict__ outx, bf16* __restrict__ xb)
{
    const int bid = blockIdx.x, t = threadIdx.x;

    if (bid >= 833) {                       // ---- scan phase A + x passthrough + xb ----
        const int sb = bid - 833;
        const int c = sb & 63, b = sb >> 6;
        const long base = ((long)b * S + (long)c * 32) * D + t * 4;
        const float* p = x + base;
        f4 s = {0.f, 0.f, 0.f, 0.f};
#pragma unroll 4
        for (int j = 0; j < 32; ++j) {
            f4 v = *(const f4*)(p + (long)j * D);
            s += v;
            *(f4*)(outx + base + (long)j * D) = v;
            short4v xp;
#pragma unroll
            for (int e = 0; e < 4; ++e) xp[e] = f2bfbits(v[e]);
            *(short4v*)((short*)xb + base + (long)j * D) = xp;
        }
        *(f4*)(part + ((long)(b * NCH + c)) * D + t * 4) = s;
        return;
    }

    if (bid == 832) {                       // ---- small stuff ----
        for (int i = t; i < 2560; i += 256) {
            int cc = i >> 9, n = i & 511;
            W2T[i] = Wcc2[(long)n * 5 + cc];
        }
        for (int i = t; i < N1; i += 256) {
            float v;
            if (i < 512)       v = b1[i];
            else if (i < 768)  v = b2[i - 512];
            else               v = b3[i - 768];
            biasA[i] = v;
        }
        return;
    }

    // ---- weight transposes ----
    const float* W; int ldw; bf16* dst; long dstLd, dstOff; int nt, kt;
    if (bid < 128)      { W = Wcc1; ldw = 512;  dst = WT1; dstLd = 1024; dstOff = 0;
                          nt = bid & 7; kt = bid >> 3; }
    else if (bid < 192) { W = Wbe1; ldw = 256;  dst = WT1; dstLd = 1024; dstOff = (long)512 * 1024;
                          int lb = bid - 128; nt = lb & 3; kt = lb >> 2; }
    else if (bid < 320) { W = Wcr1; ldw = 512;  dst = WT1; dstLd = 1024; dstOff = (long)768 * 1024;
                          int lb = bid - 192; nt = lb & 7; kt = lb >> 3; }
    else                { W = Wcd1; ldw = 1024; dst = WT2; dstLd = 2048; dstOff = 0;
                          int lb = bid - 320; nt = lb & 15; kt = lb >> 4; }

    __shared__ float tile[64][65];
    const int tx = t & 63, ty = t >> 6;
    const int k64 = kt * 64, n64 = nt * 64;
#pragma unroll
    for (int p = 0; p < 16; ++p) {
        int k = ty * 16 + p;
        tile[k][tx] = W[(long)(k64 + k) * ldw + n64 + tx];
    }
    __syncthreads();
#pragma unroll
    for (int p = 0; p < 16; ++p) {
        int n = ty * 16 + p;
        dst[dstOff + (long)(n64 + n) * dstLd + k64 + tx] = f2bf(tile[tx][n]);
    }
}

// -------- scan phase B: exclusive scan over NCH chunks + total, grouped prefetch --------
__global__ void scan_offsets2(float* __restrict__ part, float* __restrict__ total) {
    int idx = blockIdx.x * 256 + threadIdx.x;   // 8192
    int b = idx >> 10, d = idx & 1023;
    float* p = part + (long)b * NCH * D + d;
    float run = 0.f;
#pragma unroll
    for (int g = 0; g < NCH / 8; ++g) {
        float v[8];
#pragma unroll
        for (int u = 0; u < 8; ++u) v[u] = p[(long)(g * 8 + u) * D];
#pragma unroll
        for (int u = 0; u < 8; ++u) { float tv = v[u]; p[(long)(g * 8 + u) * D] = run; run += tv; }
    }
    total[idx] = run;
}

// -------- scan phase C: emit ctx (bf16x4) only (outx/xb moved to prep_scanA) --------
__global__ __launch_bounds__(256) void scan_ctx4(
    const float* __restrict__ x, const float* __restrict__ part,
    const float* __restrict__ total, bf16* __restrict__ ctxb)
{
    const int t = threadIdx.x, c = blockIdx.x, b = blockIdx.y;
    const long col = (long)t * 4;
    f4 run = *(const f4*)(part + ((long)(b * NCH + c)) * D + col);
    const f4 tot = *(const f4*)(total + (long)b * D + col);
    const long base = ((long)b * S + (long)c * 32) * D + col;
    const float invE = 1.0f / (float)(S - 1);
#pragma unroll 4
    for (int j = 0; j < 32; ++j) {
        const int s = c * 32 + j;
        f4 xv = *(const f4*)(x + base + (long)j * D);
        f4 ctx;
        if (s == 0 || s == S - 1) {
#pragma unroll
            for (int e = 0; e < 4; ++e) ctx[e] = (tot[e] - xv[e]) * invE;
        } else {
            const float invp = 1.0f / (float)s, invs = 1.0f / (float)(S - 1 - s);
#pragma unroll
            for (int e = 0; e < 4; ++e)
                ctx[e] = 0.5f * (run[e] * invp + (tot[e] - run[e] - xv[e]) * invs);
        }
        short4v cp;
#pragma unroll
        for (int e = 0; e < 4; ++e) cp[e] = f2bfbits(ctx[e]);
        *(short4v*)((short*)ctxb + base + (long)j * D) = cp;
        run += xv;
    }
}

// -------- 256x256-tile 8-phase MFMA GEMM + XCD-strip block remap (round-5/7 best) --------
// Datapath identical to the verified round-1 kernel; XCD-strip bid remap. This geometry is
// at its integer-packing optimum (per XCD: 32 heavy 2T + 40 light T blocks on 32 CUs =>
// makespan 4T ~= 139us; fractional bound 3.25T unreachable without splitting blocks, and
// smaller tiles measured 10-20% worse per-FLOP). Do not perturb.
__global__ __launch_bounds__(512) void gemm256(
    const bf16* __restrict__ Axb, const bf16* __restrict__ Actx,
    const bf16* __restrict__ WT1, const bf16* __restrict__ WT2,
    const float* __restrict__ biasA, const float* __restrict__ biasC,
    bf16* __restrict__ O1, bf16* __restrict__ O2)
{
    __shared__ __align__(16) bf16 ldsA[2][2][128 * 64];
    __shared__ __align__(16) bf16 ldsB[2][2][128 * 64];

    const int bid = blockIdx.x;
    const int xcd = bid & 7, slot = bid >> 3;
    const int gsl = slot >> 3;
    const int col_t = (gsl < 8) ? ((gsl >> 1) + ((gsl & 1) << 2)) : 8;
    const int row_t = xcd * 8 + (slot & 7);
    const int row0 = row_t * 256;
    const bool g2 = (col_t < 4);                 // heavy blocks (K=2048)
    const int col0 = (g2 ? col_t : col_t - 4) * 256;
    const int NT  = g2 ? 32 : 16;
    const int ldb = g2 ? 2048 : 1024;
    const bf16* BT = g2 ? (WT2 + (long)col0 * 2048) : (WT1 + (long)col0 * 1024);

    const int tid = threadIdx.x;
    const int w  = tid >> 6, l = tid & 63;
    const int wm = w >> 2, wn = w & 3;           // 2M x 4N waves
    const int lm = l & 15, lq = l >> 4;
    const int lr = l >> 3, cb = l & 7;
    const int ksrc = ((cb ^ lr) << 3);           // pre-swizzled source k-offset (elements)
    const int sw = lm & 7;                       // row&7 for read-side swizzle

    f32x4 acc[8][4];                             // [mh*4+i][nh*2+j]
#pragma unroll
    for (int i = 0; i < 8; ++i)
#pragma unroll
        for (int j = 0; j < 4; ++j) acc[i][j] = (f32x4){0.f, 0.f, 0.f, 0.f};

    auto stageA = [&](int t, int h) {
        if (t >= NT) return;
        const int kg = t * 64;
        const bf16* src = (kg < 1024) ? Axb : Actx;
        const int kk = kg & 1023;
        bf16* dst = &ldsA[t & 1][h][0];
#pragma unroll
        for (int q = 0; q < 2; ++q) {
            const int r = w * 16 + q * 8;        // row within the 128-row half
            async_copy16(src + (long)(row0 + h * 128 + r + lr) * 1024 + kk + ksrc,
                         dst + r * 64);
        }
    };
    auto stageB = [&](int t, int h) {
        if (t >= NT) return;
        const int kg = t * 64;
        bf16* dst = &ldsB[t & 1][h][0];
#pragma unroll
        for (int q = 0; q < 2; ++q) {
            const int r = w * 16 + q * 8;
            async_copy16(BT + (long)(h * 128 + r + lr) * ldb + kg + ksrc,
                         dst + r * 64);
        }
    };

    // prologue: tile 0 fully + tile 1 (A0,B0); leave 4 loads in flight
    stageA(0, 0); stageB(0, 0); stageB(0, 1); stageA(0, 1);
    stageA(1, 0); stageB(1, 0);
    asm volatile("s_waitcnt vmcnt(4)" ::: "memory");
    asm volatile("s_barrier" ::: "memory");

    short8 a[4][2];        // A frags of current mh half (i, ksub)
    short8 bbf[2][2][2];   // B frags, both halves held (nh, j, ksub)

    for (int u = 0; u < NT; ++u) {
        const bf16* bufA0 = &ldsA[u & 1][0][0];
        const bf16* bufA1 = &ldsA[u & 1][1][0];
        const bf16* bufB0 = &ldsB[u & 1][0][0];
        const bf16* bufB1 = &ldsB[u & 1][1][0];

        // ---- phase 1: quadrant (0,0) : read A0 + B0, stage (u+1).B1 ----
#pragma unroll
        for (int i = 0; i < 4; ++i) {
            const int ro = (wm * 64 + i * 16 + lm) * 64;
#pragma unroll
            for (int ks = 0; ks < 2; ++ks)
                a[i][ks] = *(const short8*)&bufA0[ro + (((ks * 4 + lq) ^ sw) << 3)];
        }
#pragma unroll
        for (int j = 0; j < 2; ++j) {
            const int ro = (wn * 32 + j * 16 + lm) * 64;
#pragma unroll
            for (int ks = 0; ks < 2; ++ks)
                bbf[0][j][ks] = *(const short8*)&bufB0[ro + (((ks * 4 + lq) ^ sw) << 3)];
        }
        stageB(u + 1, 1);
        asm volatile("s_barrier" ::: "memory");
        asm volatile("s_waitcnt lgkmcnt(0)" ::: "memory");
        __builtin_amdgcn_s_setprio(1);
#pragma unroll
        for (int i = 0; i < 4; ++i)
#pragma unroll
            for (int j = 0; j < 2; ++j)
#pragma unroll
                for (int ks = 0; ks < 2; ++ks)
                    acc[i][j] = __builtin_amdgcn_mfma_f32_16x16x32_bf16(a[i][ks], bbf[0][j][ks], acc[i][j], 0, 0, 0);
        __builtin_amdgcn_s_setprio(0);
        asm volatile("s_barrier" ::: "memory");

        // ---- phase 2: quadrant (0,1) : read B1, stage (u+1).A1 ----
#pragma unroll
        for (int j = 0; j < 2; ++j) {
            const int ro = (wn * 32 + j * 16 + lm) * 64;
#pragma unroll
            for (int ks = 0; ks < 2; ++ks)
                bbf[1][j][ks] = *(const short8*)&bufB1[ro + (((ks * 4 + lq) ^ sw) << 3)];
        }
        stageA(u + 1, 1);
        asm volatile("s_barrier" ::: "memory");
        asm volatile("s_waitcnt lgkmcnt(0)" ::: "memory");
        __builtin_amdgcn_s_setprio(1);
#pragma unroll
        for (int i = 0; i < 4; ++i)
#pragma unroll
            for (int j = 0; j < 2; ++j)
#pragma unroll
                for (int ks = 0; ks < 2; ++ks)
                    acc[i][2 + j] = __builtin_amdgcn_mfma_f32_16x16x32_bf16(a[i][ks], bbf[1][j][ks], acc[i][2 + j], 0, 0, 0);
        __builtin_amdgcn_s_setprio(0);
        asm volatile("s_barrier" ::: "memory");

        // ---- phase 3: quadrant (1,0) : read A1, stage (u+2).A0 ----
#pragma unroll
        for (int i = 0; i < 4; ++i) {
            const int ro = (wm * 64 + i * 16 + lm) * 64;
#pragma unroll
            for (int ks = 0; ks < 2; ++ks)
                a[i][ks] = *(const short8*)&bufA1[ro + (((ks * 4 + lq) ^ sw) << 3)];
        }
        stageA(u + 2, 0);
        asm volatile("s_barrier" ::: "memory");
        asm volatile("s_waitcnt lgkmcnt(0)" ::: "memory");
        __builtin_amdgcn_s_setprio(1);
#pragma unroll
        for (int i = 0; i < 4; ++i)
#pragma unroll
            for (int j = 0; j < 2; ++j)
#pragma unroll
                for (int ks = 0; ks < 2; ++ks)
                    acc[4 + i][j] = __builtin_amdgcn_mfma_f32_16x16x32_bf16(a[i][ks], bbf[0][j][ks], acc[4 + i][j], 0, 0, 0);
        __builtin_amdgcn_s_setprio(0);
        asm volatile("s_barrier" ::: "memory");

        // ---- phase 4: quadrant (1,1) : stage (u+2).B0, counted vmcnt ----
        stageB(u + 2, 0);
        asm volatile("s_barrier" ::: "memory");
        asm volatile("s_waitcnt lgkmcnt(0)" ::: "memory");
        __builtin_amdgcn_s_setprio(1);
#pragma unroll
        for (int i = 0; i < 4; ++i)
#pragma unroll
            for (int j = 0; j < 2; ++j)
#pragma unroll
                for (int ks = 0; ks < 2; ++ks)
                    acc[4 + i][2 + j] = __builtin_amdgcn_mfma_f32_16x16x32_bf16(a[i][ks], bbf[1][j][ks], acc[4 + i][2 + j], 0, 0, 0);
        __builtin_amdgcn_s_setprio(0);
        if (u + 2 < NT) asm volatile("s_waitcnt vmcnt(4)" ::: "memory");
        else            asm volatile("s_waitcnt vmcnt(0)" ::: "memory");
        asm volatile("s_barrier" ::: "memory");
    }

    // ---- C write: bias + optional relu, bf16 out ----
    bf16* O = g2 ? O2 : O1;
    const long ldo = g2 ? 1024 : N1;
    const float* bias = g2 ? biasC : biasA;
    const int reluN = g2 ? 0 : 768;
#pragma unroll
    for (int mh = 0; mh < 2; ++mh)
#pragma unroll
        for (int i = 0; i < 4; ++i)
#pragma unroll
            for (int nh = 0; nh < 2; ++nh)
#pragma unroll
                for (int j = 0; j < 2; ++j) {
                    const int col = col0 + nh * 128 + wn * 32 + j * 16 + lm;
                    const float bv = bias[col];
                    const bool rl = col < reluN;
                    const f32x4 av = acc[mh * 4 + i][nh * 2 + j];
#pragma unroll
                    for (int r = 0; r < 4; ++r) {
                        const int row = row0 + mh * 128 + wm * 64 + i * 16 + lq * 4 + r;
                        float v = av[r] + bv;
                        if (rl) v = fmaxf(v, 0.f);
                        O[(long)row * ldo + col] = f2bf(v);
                    }
                }
}

// -------- fused epilogue: softmax + be2 + cr2 + LN/gelu/cd2, wave per row --------
__global__ __launch_bounds__(256) void epilogue(
    const bf16* __restrict__ YB, const bf16* __restrict__ H,
    const float* __restrict__ W2T, const float* __restrict__ b2,
    const float* __restrict__ Wbe, const float* __restrict__ bbe,
    const float* __restrict__ W5, const float* __restrict__ Wcr, const float* __restrict__ bcr,
    const float* __restrict__ g, const float* __restrict__ be,
    const float* __restrict__ Wd, const float* __restrict__ bd,
    float* __restrict__ out_ct, float* __restrict__ out_enh, float* __restrict__ out_wb,
    float* __restrict__ out_rel, float* __restrict__ out_cred)
{
    const int w = threadIdx.x >> 6, l = threadIdx.x & 63;
    const long r = (long)blockIdx.x * 4 + w;
    const bf16* yrow = YB + r * N1;

    // ---- content-type softmax (cc2) ----
    short8 y1 = *(const short8*)(yrow + l * 8);
    float yv[8];
#pragma unroll
    for (int j = 0; j < 8; ++j) yv[j] = bits2f(y1[j]);
    float s5[5];
#pragma unroll
    for (int cc = 0; cc < 5; ++cc) {
        f4 wa = *(const f4*)(W2T + cc * 512 + l * 8);
        f4 wb = *(const f4*)(W2T + cc * 512 + l * 8 + 4);
        float a = 0.f;
#pragma unroll
        for (int j = 0; j < 4; ++j) a += yv[j] * wa[j];
#pragma unroll
        for (int j = 0; j < 4; ++j) a += yv[4 + j] * wb[j];
        s5[cc] = a;
    }
#pragma unroll
    for (int cc = 0; cc < 5; ++cc) s5[cc] = wsum(s5[cc]) + b2[cc];
    float mx = s5[0];
#pragma unroll
    for (int cc = 1; cc < 5; ++cc) mx = fmaxf(mx, s5[cc]);
    float ct[5]; float den = 0.f;
#pragma unroll
    for (int cc = 0; cc < 5; ++cc) { ct[cc] = expf(s5[cc] - mx); den += ct[cc]; }
    float inv = 1.f / den;
#pragma unroll
    for (int cc = 0; cc < 5; ++cc) ct[cc] *= inv;
    if (l < 5) out_ct[r * 5 + l] = ct[l];
    if (l == 0) out_rel[r] = 1.f - ct[3];

    // ---- bias path (be2) ----
    short4v y3 = *(const short4v*)(yrow + 512 + l * 4);
    f4 wv = *(const f4*)(Wbe + l * 4);
    float sb = 0.f;
#pragma unroll
    for (int j = 0; j < 4; ++j) sb += bits2f(y3[j]) * wv[j];
    sb = wsum(sb);
    if (l == 0) {
        float sig = 1.f / (1.f + expf(-(sb + bbe[0])));
        float cb = 0.1f * ct[0] + 1.0f * ct[1] + 0.8f * ct[2] + 0.3f * ct[3] + 0.5f * ct[4];
        out_wb[r] = sig * cb;
    }

    // ---- credibility (cr2, rank-5 ct correction + relu + dot) ----
    short8 y4 = *(const short8*)(yrow + 768 + l * 8);
    float corr[8] = {0, 0, 0, 0, 0, 0, 0, 0};
#pragma unroll
    for (int cc = 0; cc < 5; ++cc) {
        f4 a = *(const f4*)(W5 + cc * 512 + l * 8);
        f4 b = *(const f4*)(W5 + cc * 512 + l * 8 + 4);
#pragma unroll
        for (int j = 0; j < 4; ++j) { corr[j] += ct[cc] * a[j]; corr[4 + j] += ct[cc] * b[j]; }
    }
    f4 wca = *(const f4*)(Wcr + l * 8);
    f4 wcb = *(const f4*)(Wcr + l * 8 + 4);
    float scr = 0.f;
#pragma unroll
    for (int j = 0; j < 4; ++j) scr += fmaxf(bits2f(y4[j]) + corr[j], 0.f) * wca[j];
#pragma unroll
    for (int j = 0; j < 4; ++j) scr += fmaxf(bits2f(y4[4 + j]) + corr[4 + j], 0.f) * wcb[j];
    scr = wsum(scr);
    if (l == 0) out_cred[r] = 1.f / (1.f + expf(-(scr + bcr[0])));

    // ---- LN + gelu + cd2 (lane owns elements l*8 + c*512, c=0,1) ----
    const bf16* hrow = H + r * 1024;
    float v[16];
    float sum = 0.f, sum2 = 0.f;
#pragma unroll
    for (int c = 0; c < 2; ++c) {
        short8 hh = *(const short8*)(hrow + c * 512 + l * 8);
#pragma unroll
        for (int j = 0; j < 8; ++j) {
            float f = bits2f(hh[j]);
            v[c * 8 + j] = f;
            sum += f; sum2 += f * f;
        }
    }
    sum = wsum(sum);
    sum2 = wsum(sum2);
    float mu = sum * (1.f / 1024.f);
    float var = sum2 * (1.f / 1024.f) - mu * mu;
    float rstd = rsqrtf(var + 1e-5f);
    float dot = 0.f;
#pragma unroll
    for (int c = 0; c < 2; ++c) {
        int base = c * 512 + l * 8;
        f4 ga = *(const f4*)(g + base),  gb = *(const f4*)(g + base + 4);
        f4 ba = *(const f4*)(be + base), bb = *(const f4*)(be + base + 4);
        f4 wa = *(const f4*)(Wd + base), wb = *(const f4*)(Wd + base + 4);
#pragma unroll
        for (int j = 0; j < 4; ++j) {
            float hn = (v[c * 8 + j] - mu) * rstd * ga[j] + ba[j];
            float ge = 0.5f * hn * (1.f + erff(hn * 0.70710678118654752f));
            dot += ge * wa[j];
            float hn2 = (v[c * 8 + 4 + j] - mu) * rstd * gb[j] + bb[j];
            float ge2 = 0.5f * hn2 * (1.f + erff(hn2 * 0.70710678118654752f));
            dot += ge2 * wb[j];
        }
    }
    dot = wsum(dot);
    if (l == 0) {
        float contr = 1.f / (1.f + expf(-(dot + bd[0])));
        out_enh[r] = fmaxf(contr, ct[2]);
    }
}

extern "C" void kernel_launch(void* const* d_in, const int* in_sizes, int n_in,
                              void* d_out, int out_size, void* d_ws, size_t ws_size,
                              hipStream_t stream) {
    const float* x      = (const float*)d_in[0];
    const float* W_cc1  = (const float*)d_in[1];
    const float* b_cc1  = (const float*)d_in[2];
    const float* W_cc2  = (const float*)d_in[3];
    const float* b_cc2  = (const float*)d_in[4];
    const float* W_cd1  = (const float*)d_in[5];
    const float* b_cd1  = (const float*)d_in[6];
    const float* g_ln   = (const float*)d_in[7];
    const float* be_ln  = (const float*)d_in[8];
    const float* W_cd2  = (const float*)d_in[9];
    const float* b_cd2  = (const float*)d_in[10];
    const float* W_be1  = (const float*)d_in[11];
    const float* b_be1  = (const float*)d_in[12];
    const float* W_be2  = (const float*)d_in[13];
    const float* b_be2  = (const float*)d_in[14];
    const float* W_cr1  = (const float*)d_in[15];
    const float* b_cr1  = (const float*)d_in[16];
    const float* W_cr2  = (const float*)d_in[17];
    const float* b_cr2  = (const float*)d_in[18];

    float* out = (float*)d_out;
    float* out_x    = out;
    float* out_ct   = out_x + (long)ROWS * D;
    float* out_enh  = out_ct + ROWS * 5;
    float* out_wb   = out_enh + ROWS;
    float* out_rel  = out_wb + ROWS;
    float* out_cred = out_rel + ROWS;

    char* cur = (char*)d_ws;
    auto alloc = [&](size_t bytes) { char* p = cur; cur += (bytes + 255) & ~(size_t)255; return p; };

    bf16* WT1    = (bf16*)alloc((size_t)N1 * 1024 * 2);     // [1280][1024]
    bf16* WT2    = (bf16*)alloc((size_t)1024 * 2048 * 2);   // [1024][2048] cd1 full
    float* W2T   = (float*)alloc((size_t)5 * 512 * 4);
    float* biasA = (float*)alloc((size_t)N1 * 4);
    bf16* xb     = (bf16*)alloc((size_t)ROWS * 1024 * 2);
    bf16* ctxb   = (bf16*)alloc((size_t)ROWS * 1024 * 2);
    bf16* YB     = (bf16*)alloc((size_t)ROWS * N1 * 2);     // 40 MB
    bf16* Hbuf   = (bf16*)alloc((size_t)ROWS * 1024 * 2);   // 32 MB
    float* part  = (float*)alloc((size_t)Bb * NCH * 1024 * 4);
    float* totl  = (float*)alloc((size_t)Bb * 1024 * 4);

    // merged: weight prep (blocks 0-832) + scan phase A with outx/xb emission (833-1344)
    prep_scanA<<<833 + NCH * Bb, 256, 0, stream>>>(
        W_cc1, W_be1, W_cr1, W_cd1, W_cc2,
        b_cc1, b_be1, b_cr1, WT1, WT2, W2T, biasA,
        x, part, out_x, xb);

    scan_offsets2<<<32, 256, 0, stream>>>(part, totl);
    scan_ctx4<<<dim3(NCH, Bb), 256, 0, stream>>>(x, part, totl, ctxb);

    // 256x256 8-phase GEMM (best) with XCD-strip remap:
    //   g2 cols (K=2048) -> Hbuf; g1 cols (K=1024) -> YB
    gemm256<<<dim3(9 * MT2), 512, 0, stream>>>(
        xb, ctxb, WT1, WT2, biasA, b_cd1, YB, Hbuf);

    // fused epilogue (softmax, be2, cr2, LN+gelu+cd2)
    epilogue<<<ROWS / 4, 256, 0, stream>>>(
        YB, Hbuf, W2T, b_cc2, W_be2, b_be2,
        W_cr1 + (long)1024 * 512, W_cr2, b_cr2,
        g_ln, be_ln, W_cd2, b_cd2,
        out_ct, out_enh, out_wb, out_rel, out_cred);

    (void)in_sizes; (void)n_in; (void)out_size; (void)ws_size;
}